// Round 11
// baseline (43.897 us; speedup 1.0000x reference)
//
#include <hip/hip_runtime.h>
#include <math.h>

// DegradedBicycleRollout: b=512, l=64, h=80, state=12.
// R11: isolate DRAM write-segment size. SPC 8 -> 20 (flush segments 384B ->
// 960B per 3888B l-row), dbuf 2x64x61 f4 = 122KB LDS -> 1 block/CU (512
// blocks = 2 pipelined rounds). 4 waves: compute + 3 writers (20 slices each).
// Ctl loads return to compute wave (R3-style group prefetch; R8 proved the
// ctl path neutral). R10 post-mortem: store concurrency neutral; only
// never-isolated variable left is write-stream locality vs the fill kernel's
// 6.8 TB/s linear stream.

#define N_B 512
#define N_L 64
#define N_H 80
#define DT_F 0.1f
#define PITCH_F4 61       // 60 used + 1 pad (odd -> distinct bank phases)
#define SPC 20            // steps per chunk
#define NCH 4             // chunks
#define INV2PI 0.15915494309189535f

__device__ __forceinline__ float fast_rcp(float x) { return __builtin_amdgcn_rcpf(x); }

__device__ __forceinline__ float fast_tanh(float x) {
    const float e2 = __expf(2.0f * x);
    return (e2 - 1.0f) * fast_rcp(e2 + 1.0f);
}

__device__ __forceinline__ float fast_sigmoid(float x) {
    return fast_rcp(1.0f + __expf(-x));
}

__device__ __forceinline__ float fast_atan_small(float z) {
    // |z| <= 0.42; odd Taylor through z^9, max err ~1e-5.
    const float z2 = z * z;
    float p = 1.0f / 9.0f;
    p = fmaf(p, z2, -1.0f / 7.0f);
    p = fmaf(p, z2, 1.0f / 5.0f);
    p = fmaf(p, z2, -1.0f / 3.0f);
    p = fmaf(p, z2, 1.0f);
    return z * p;
}

__device__ __forceinline__ float fast_tan_075(float x) {
    // tan(x) on |x|<=0.75, odd Taylor through x^13; max err ~3e-5 at edge.
    const float x2 = x * x;
    float p = 0.0035916f;
    p = fmaf(p, x2, 0.0088632f);
    p = fmaf(p, x2, 0.0218695f);
    p = fmaf(p, x2, 0.0539683f);
    p = fmaf(p, x2, 0.1333333f);
    p = fmaf(p, x2, 0.3333333f);
    return fmaf(p * x2, x, x);
}

struct Ctl { float delta, fb, fx, tan_d, beta, acc; };

__device__ __forceinline__ Ctl make_ctl(float u0, float u1, float u2,
                                        float steer_scale, float brake_scale,
                                        float throttle_scale, float neg_brake_lim) {
    Ctl t;
    t.delta = steer_scale * fast_tanh(u0);
    t.fb = brake_scale    * fast_sigmoid(u1);
    t.fx = throttle_scale * fast_sigmoid(u2);
    const float dc = fminf(fmaxf(t.delta, -0.75f), 0.75f);
    t.tan_d = fast_tan_075(dc);
    t.beta = fminf(fmaxf(fast_atan_small(0.45f * t.tan_d), -0.65f), 0.65f);
    t.acc = fminf(fmaxf(2.8f * t.fx - 6.5f * t.fb, neg_brake_lim), 3.0f);
    return t;
}

__global__ __launch_bounds__(256) void degraded_bicycle_rollout_kernel(
    const float* __restrict__ x0,        // [512,12]
    const float* __restrict__ controls,  // [512,64,80,3]
    const float* __restrict__ deg,       // [512,5]
    float* __restrict__ out)             // [512,64,81,12]
{
    __shared__ float4 lds4[2][N_L * PITCH_F4];   // 2 x 61 KB

    const int lane = threadIdx.x & 63;
    const int wv   = threadIdx.x >> 6;        // 0=compute, 1..3=writers
    const int b = blockIdx.x;                 // one b per block

    const size_t out_b = (size_t)b * 62208;   // b*64*972 floats

    // flush f4-slices [I0,I1) of chunk FC from buffer FBUF (lane-coalesced)
#define FLUSH_SLICE(FBUF, FC, I0, I1)                                             \
    {                                                                             \
        const size_t obase = out_b + 12 + (size_t)(FC) * (SPC * 12);              \
        _Pragma("unroll")                                                         \
        for (int i = (I0); i < (I1); ++i) {                                       \
            const unsigned flat = i * 64 + lane;                                  \
            const unsigned l = flat / 60u;                                        \
            const unsigned q = flat - l * 60u;                                    \
            const float4 v = lds4[FBUF][l * PITCH_F4 + q];                        \
            *reinterpret_cast<float4*>(out + obase + (size_t)l * 972 + q * 4) = v;\
        }                                                                         \
    }

    if (wv == 0) {
        // ================= compute persona =================
        const float* dg = deg + b * 5;
        const float steer_scale    = fmaxf(dg[0], 0.05f);
        const float brake_scale    = fmaxf(dg[1], 0.05f);
        const float throttle_scale = fmaxf(dg[2], 0.05f);
        const float friction       = fmaxf(dg[4], 0.1f);

        const float4* x0v = reinterpret_cast<const float4*>(x0 + b * 12);
        const float4 xi0 = x0v[0];
        const float4 xi1 = x0v[1];

        float px  = xi0.x;
        float py  = xi0.y;
        float psi = xi0.z;
        float vxp = xi0.w;
        float vyp = xi1.x;
        float s = __builtin_amdgcn_sqrtf(fmaf(vxp, vxp, fmaf(vyp, vyp, 1e-6f)));

        const float neg_brake_lim = -7.5f * friction;
        const float yaw_num = friction * 9.81f;
        const float inv_wheelbase = 1.0f / 2.8f;

        const int tid = b * 64 + lane;
        const float4* uc = reinterpret_cast<const float4*>(controls + (size_t)tid * 240);

        // prefetch group 0 controls (3 f4 = 4 steps)
        float4 c0 = uc[0];
        float4 c1 = uc[1];
        float4 c2 = uc[2];

        for (int c = 0; c < NCH; ++c) {       // 4 chunks x 20 steps
            float4* lrow = &lds4[c & 1][lane * PITCH_F4];

            #pragma unroll
            for (int gg = 0; gg < 5; ++gg) {  // 5 groups of 4 steps
                const int g = c * 5 + gg;
                float4 n0 = c0, n1 = c1, n2 = c2;
                if (g < 19) {
                    n0 = uc[(g + 1) * 3 + 0];
                    n1 = uc[(g + 1) * 3 + 1];
                    n2 = uc[(g + 1) * 3 + 2];
                }

                const Ctl tA = make_ctl(c0.x, c0.y, c0.z, steer_scale, brake_scale, throttle_scale, neg_brake_lim);
                const Ctl tB = make_ctl(c0.w, c1.x, c1.y, steer_scale, brake_scale, throttle_scale, neg_brake_lim);
                const Ctl tC = make_ctl(c1.z, c1.w, c2.x, steer_scale, brake_scale, throttle_scale, neg_brake_lim);
                const Ctl tD = make_ctl(c2.y, c2.z, c2.w, steer_scale, brake_scale, throttle_scale, neg_brake_lim);

#define ROLL_STEP(T, RR)                                                          \
                {                                                                 \
                    const float s2 = fmaxf(fmaf((T).acc, DT_F, s), 0.0f);         \
                    const float raw_yaw = s2 * inv_wheelbase * (T).tan_d;         \
                    const float yaw_lim = fmaxf(yaw_num * fast_rcp(fmaxf(s2, 2.0f)), 0.15f); \
                    const float yaw_rate = fminf(fmaxf(raw_yaw, -1.0f), 1.0f) * yaw_lim; \
                    const float psi2 = fmaf(yaw_rate, DT_F, psi);                 \
                    const float ang = (psi2 + (T).beta) * INV2PI;                 \
                    const float sn = __builtin_amdgcn_sinf(ang);                  \
                    const float cs = __builtin_amdgcn_cosf(ang);                  \
                    const float vx2 = s2 * cs;                                    \
                    const float vy2 = s2 * sn;                                    \
                    const float px2 = fmaf(vx2, DT_F, px);                        \
                    const float py2 = fmaf(vy2, DT_F, py);                        \
                    const float ax = (vx2 - vxp) * 10.0f;                         \
                    const float ay = (vy2 - vyp) * 10.0f;                         \
                    lrow[(RR) * 3 + 0] = make_float4(px2, py2, psi2, vx2);        \
                    lrow[(RR) * 3 + 1] = make_float4(vy2, yaw_rate, ax, ay);      \
                    lrow[(RR) * 3 + 2] = make_float4((T).beta, (T).delta, (T).fb, (T).fx); \
                    s = __builtin_amdgcn_sqrtf(fmaf(s2, s2, 1e-6f));              \
                    px = px2; py = py2; psi = psi2; vxp = vx2; vyp = vy2;         \
                }

                ROLL_STEP(tA, gg * 4 + 0)
                ROLL_STEP(tB, gg * 4 + 1)
                ROLL_STEP(tC, gg * 4 + 2)
                ROLL_STEP(tD, gg * 4 + 3)
#undef ROLL_STEP

                c0 = n0; c1 = n1; c2 = n2;
            }
            __syncthreads();   // chunk c staged; writers done with buf[c&1]
        }
    } else {
        // ============ writers 1..3: flush 20 slices each ============
        const int i0 = (wv - 1) * 20;
        if (wv == 2) {
            // h=0 rows (one-time, during prologue slack)
            const float4* x0v = reinterpret_cast<const float4*>(x0 + b * 12);
            const float4 xq0 = x0v[0];
            const float4 xq1 = x0v[1];
            const float4 xq2 = x0v[2];
            #pragma unroll
            for (int i = 0; i < 3; ++i) {
                const unsigned flat = i * 64 + lane;
                const unsigned l = flat / 3u;
                const unsigned q = flat - l * 3u;
                const float4 v = (q == 0) ? xq0 : (q == 1) ? xq1 : xq2;
                *reinterpret_cast<float4*>(out + out_b + (size_t)l * 972 + q * 4) = v;
            }
        }

        for (int c = 0; c < NCH; ++c) {
            __syncthreads();   // wait for chunk c to be staged
            // flush chunk c while compute works on c+1 (dbuf: safe until the
            // barrier at end of chunk c+1, which is our NEXT loop iteration's
            // __syncthreads -- so flush must complete before then; it does,
            // writers' only work is this flush)
            if (c + 1 < NCH) {
                FLUSH_SLICE(c & 1, c, i0, i0 + 20)
            } else {
                FLUSH_SLICE(c & 1, c, i0, i0 + 20)
            }
        }
    }
#undef FLUSH_SLICE
}

extern "C" void kernel_launch(void* const* d_in, const int* in_sizes, int n_in,
                              void* d_out, int out_size, void* d_ws, size_t ws_size,
                              hipStream_t stream) {
    (void)in_sizes; (void)n_in; (void)d_ws; (void)ws_size; (void)out_size;
    const float* x0       = (const float*)d_in[0];
    const float* controls = (const float*)d_in[1];
    const float* deg      = (const float*)d_in[2];
    float* out            = (float*)d_out;

    dim3 grid(N_B), block(256);               // 512 blocks x 4 waves, 1 block/CU
    hipLaunchKernelGGL(degraded_bicycle_rollout_kernel, grid, block, 0, stream,
                       x0, controls, deg, out);
}

// Round 12
// 34.626 us; speedup vs baseline: 1.2677x; 1.2677x over previous
//
#include <hip/hip_runtime.h>
#include <math.h>

// DegradedBicycleRollout: b=512, l=64, h=80, state=12.
// R12: R11 post-mortem -- a block alone on a CU finishes in ~22us (R11 rounds),
// but 2 co-resident blocks each take ~35us => the two compute waves (both
// wave-slot 0 of their block) contend for the SAME SIMD's issue port.
// Fix: one block per CU (grid=256), each handling TWO b's with TWO compute
// waves at block-wave slots 0 and 1 -> different SIMDs. 6 writer waves
// (3 per b) flush coalesced. LDS 2b x dbuf x 64 x 25 f4 = 102.4KB -> 1 block/CU.

#define N_B 512
#define N_L 64
#define N_H 80
#define DT_F 0.1f
#define PITCH_F4 25       // 24 used + 1 pad
#define SPC 8             // steps per chunk
#define NCH 10            // chunks
#define INV2PI 0.15915494309189535f

__device__ __forceinline__ float fast_rcp(float x) { return __builtin_amdgcn_rcpf(x); }

__device__ __forceinline__ float fast_tanh(float x) {
    const float e2 = __expf(2.0f * x);
    return (e2 - 1.0f) * fast_rcp(e2 + 1.0f);
}

__device__ __forceinline__ float fast_sigmoid(float x) {
    return fast_rcp(1.0f + __expf(-x));
}

__device__ __forceinline__ float fast_atan_small(float z) {
    // |z| <= 0.42; odd Taylor through z^9, max err ~1e-5.
    const float z2 = z * z;
    float p = 1.0f / 9.0f;
    p = fmaf(p, z2, -1.0f / 7.0f);
    p = fmaf(p, z2, 1.0f / 5.0f);
    p = fmaf(p, z2, -1.0f / 3.0f);
    p = fmaf(p, z2, 1.0f);
    return z * p;
}

__device__ __forceinline__ float fast_tan_075(float x) {
    // tan(x) on |x|<=0.75, odd Taylor through x^13; max err ~3e-5 at edge.
    const float x2 = x * x;
    float p = 0.0035916f;
    p = fmaf(p, x2, 0.0088632f);
    p = fmaf(p, x2, 0.0218695f);
    p = fmaf(p, x2, 0.0539683f);
    p = fmaf(p, x2, 0.1333333f);
    p = fmaf(p, x2, 0.3333333f);
    return fmaf(p * x2, x, x);
}

struct Ctl { float delta, fb, fx, tan_d, beta, acc; };

__device__ __forceinline__ Ctl make_ctl(float u0, float u1, float u2,
                                        float steer_scale, float brake_scale,
                                        float throttle_scale, float neg_brake_lim) {
    Ctl t;
    t.delta = steer_scale * fast_tanh(u0);
    t.fb = brake_scale    * fast_sigmoid(u1);
    t.fx = throttle_scale * fast_sigmoid(u2);
    const float dc = fminf(fmaxf(t.delta, -0.75f), 0.75f);
    t.tan_d = fast_tan_075(dc);
    t.beta = fminf(fmaxf(fast_atan_small(0.45f * t.tan_d), -0.65f), 0.65f);
    t.acc = fminf(fmaxf(2.8f * t.fx - 6.5f * t.fb, neg_brake_lim), 3.0f);
    return t;
}

__global__ __launch_bounds__(512) void degraded_bicycle_rollout_kernel(
    const float* __restrict__ x0,        // [512,12]
    const float* __restrict__ controls,  // [512,64,80,3]
    const float* __restrict__ deg,       // [512,5]
    float* __restrict__ out)             // [512,64,81,12]
{
    __shared__ float4 lds4[2][2][N_L * PITCH_F4];   // [bb][buf] 102.4 KB total

    const int lane = threadIdx.x & 63;
    const int wv   = threadIdx.x >> 6;        // 0..7

    // persona mapping:
    //   wv 0,1        -> compute waves for bb=0,1 (SIMD 0,1 by slot assignment)
    //   wv 2..7       -> writers; bb=(wv-2)&1, slot=(wv-2)>>1 in {0,1,2}
    const bool is_compute = (wv < 2);
    const int bb   = is_compute ? wv : ((wv - 2) & 1);
    const int slot = is_compute ? 0  : ((wv - 2) >> 1);

    const int b = blockIdx.x * 2 + bb;
    const size_t out_b = (size_t)b * 62208;   // b*64*972 floats

#define FLUSH_SLICE(BB, FBUF, FC, I0, I1)                                         \
    {                                                                             \
        const size_t obase = out_b + 12 + (size_t)(FC) * (SPC * 12);              \
        _Pragma("unroll")                                                         \
        for (int i = (I0); i < (I1); ++i) {                                       \
            const unsigned flat = i * 64 + lane;                                  \
            const unsigned l = flat / 24u;                                        \
            const unsigned q = flat - l * 24u;                                    \
            const float4 v = lds4[BB][FBUF][l * PITCH_F4 + q];                    \
            *reinterpret_cast<float4*>(out + obase + (size_t)l * 972 + q * 4) = v;\
        }                                                                         \
    }

    if (is_compute) {
        // ================= compute persona (one per b) =================
        const float* dg = deg + b * 5;
        const float steer_scale    = fmaxf(dg[0], 0.05f);
        const float brake_scale    = fmaxf(dg[1], 0.05f);
        const float throttle_scale = fmaxf(dg[2], 0.05f);
        const float friction       = fmaxf(dg[4], 0.1f);

        const float4* x0v = reinterpret_cast<const float4*>(x0 + b * 12);
        const float4 xi0 = x0v[0];
        const float4 xi1 = x0v[1];

        float px  = xi0.x;
        float py  = xi0.y;
        float psi = xi0.z;
        float vxp = xi0.w;
        float vyp = xi1.x;
        float s = __builtin_amdgcn_sqrtf(fmaf(vxp, vxp, fmaf(vyp, vyp, 1e-6f)));

        const float neg_brake_lim = -7.5f * friction;
        const float yaw_num = friction * 9.81f;
        const float inv_wheelbase = 1.0f / 2.8f;

        const int tid = b * 64 + lane;
        const float4* uc = reinterpret_cast<const float4*>(controls + (size_t)tid * 240);

        // prefetch group 0 controls (3 f4 = 4 steps)
        float4 c0 = uc[0];
        float4 c1 = uc[1];
        float4 c2 = uc[2];

        for (int c = 0; c < NCH; ++c) {       // 10 chunks x 8 steps
            float4* lrow = &lds4[bb][c & 1][lane * PITCH_F4];

            #pragma unroll
            for (int gg = 0; gg < 2; ++gg) {  // 2 groups of 4 steps
                const int g = c * 2 + gg;
                float4 n0 = c0, n1 = c1, n2 = c2;
                if (g < 19) {
                    n0 = uc[(g + 1) * 3 + 0];
                    n1 = uc[(g + 1) * 3 + 1];
                    n2 = uc[(g + 1) * 3 + 2];
                }

                const Ctl tA = make_ctl(c0.x, c0.y, c0.z, steer_scale, brake_scale, throttle_scale, neg_brake_lim);
                const Ctl tB = make_ctl(c0.w, c1.x, c1.y, steer_scale, brake_scale, throttle_scale, neg_brake_lim);
                const Ctl tC = make_ctl(c1.z, c1.w, c2.x, steer_scale, brake_scale, throttle_scale, neg_brake_lim);
                const Ctl tD = make_ctl(c2.y, c2.z, c2.w, steer_scale, brake_scale, throttle_scale, neg_brake_lim);

#define ROLL_STEP(T, RR)                                                          \
                {                                                                 \
                    const float s2 = fmaxf(fmaf((T).acc, DT_F, s), 0.0f);         \
                    const float raw_yaw = s2 * inv_wheelbase * (T).tan_d;         \
                    const float yaw_lim = fmaxf(yaw_num * fast_rcp(fmaxf(s2, 2.0f)), 0.15f); \
                    const float yaw_rate = fminf(fmaxf(raw_yaw, -1.0f), 1.0f) * yaw_lim; \
                    const float psi2 = fmaf(yaw_rate, DT_F, psi);                 \
                    const float ang = (psi2 + (T).beta) * INV2PI;                 \
                    const float sn = __builtin_amdgcn_sinf(ang);                  \
                    const float cs = __builtin_amdgcn_cosf(ang);                  \
                    const float vx2 = s2 * cs;                                    \
                    const float vy2 = s2 * sn;                                    \
                    const float px2 = fmaf(vx2, DT_F, px);                        \
                    const float py2 = fmaf(vy2, DT_F, py);                        \
                    const float ax = (vx2 - vxp) * 10.0f;                         \
                    const float ay = (vy2 - vyp) * 10.0f;                         \
                    lrow[(RR) * 3 + 0] = make_float4(px2, py2, psi2, vx2);        \
                    lrow[(RR) * 3 + 1] = make_float4(vy2, yaw_rate, ax, ay);      \
                    lrow[(RR) * 3 + 2] = make_float4((T).beta, (T).delta, (T).fb, (T).fx); \
                    s = __builtin_amdgcn_sqrtf(fmaf(s2, s2, 1e-6f));              \
                    px = px2; py = py2; psi = psi2; vxp = vx2; vyp = vy2;         \
                }

                ROLL_STEP(tA, gg * 4 + 0)
                ROLL_STEP(tB, gg * 4 + 1)
                ROLL_STEP(tC, gg * 4 + 2)
                ROLL_STEP(tD, gg * 4 + 3)
#undef ROLL_STEP

                c0 = n0; c1 = n1; c2 = n2;
            }
            __syncthreads();   // chunk c staged for this b (and the other b)
        }
        // writers flush chunk NCH-1 after the final barrier
    } else {
        // ============ writer personas: 3 per b, 8 slices each ============
        const int i0 = slot * 8;
        if (slot == 0) {
            // h=0 rows for this b (one-time, prologue slack)
            const float4* x0v = reinterpret_cast<const float4*>(x0 + b * 12);
            const float4 xq0 = x0v[0];
            const float4 xq1 = x0v[1];
            const float4 xq2 = x0v[2];
            #pragma unroll
            for (int i = 0; i < 3; ++i) {
                const unsigned flat = i * 64 + lane;
                const unsigned l = flat / 3u;
                const unsigned q = flat - l * 3u;
                const float4 v = (q == 0) ? xq0 : (q == 1) ? xq1 : xq2;
                *reinterpret_cast<float4*>(out + out_b + (size_t)l * 972 + q * 4) = v;
            }
        }

        for (int c = 0; c < NCH; ++c) {
            __syncthreads();   // chunk c staged by compute waves
            // flush chunk c while compute works on c+1. Safe: compute reuses
            // buf[c&1] only for chunk c+2, which starts after barrier c+1 --
            // and we reach barrier c+1 only after this flush completes.
            FLUSH_SLICE(bb, c & 1, c, i0, i0 + 8)
        }
    }
#undef FLUSH_SLICE
}

extern "C" void kernel_launch(void* const* d_in, const int* in_sizes, int n_in,
                              void* d_out, int out_size, void* d_ws, size_t ws_size,
                              hipStream_t stream) {
    (void)in_sizes; (void)n_in; (void)d_ws; (void)ws_size; (void)out_size;
    const float* x0       = (const float*)d_in[0];
    const float* controls = (const float*)d_in[1];
    const float* deg      = (const float*)d_in[2];
    float* out            = (float*)d_out;

    dim3 grid(N_B / 2), block(512);           // 256 blocks (1/CU) x 8 waves
    hipLaunchKernelGGL(degraded_bicycle_rollout_kernel, grid, block, 0, stream,
                       x0, controls, deg, out);
}